// Round 7
// baseline (209.832 us; speedup 1.0000x reference)
//
#include <hip/hip_runtime.h>
#include <hip/hip_bf16.h>

#define IN_DIM 128
#define HID_DIM 64
#define OUT_DIM 16

// Stripe/bin geometry: 128 nodes per stripe
#define SSHIFT 7
#define SMASK 127
// Edge chunking for passes A/C: 245 blocks -> all CUs busy
#define CHUNK 4096
#define CBLK 256

// bf16 helpers: round-to-nearest-even pack, bit-shift unpack
static __device__ __forceinline__ unsigned short f2bf(float f) {
    unsigned u = __float_as_uint(f);
    unsigned r = u + 0x7fffu + ((u >> 16) & 1u);
    return (unsigned short)(r >> 16);
}
static __device__ __forceinline__ unsigned packbf2(float a, float b) {
    return (unsigned)f2bf(a) | ((unsigned)f2bf(b) << 16);
}
static __device__ __forceinline__ float bflo(unsigned v) { return __uint_as_float(v << 16); }
static __device__ __forceinline__ float bfhi(unsigned v) { return __uint_as_float(v & 0xffff0000u); }

// ---------------------------------------------------------------------------
// passA: per-block per-stripe histogram (LDS only, no global atomics)
// ---------------------------------------------------------------------------
__global__ __launch_bounds__(CBLK) void passA(const int* __restrict__ dst,
                                              int* __restrict__ cm,
                                              int E, int NS, int NSP) {
    __shared__ int cnt[512];
    int t = threadIdx.x;
    for (int s = t; s < NS; s += CBLK) cnt[s] = 0;
    __syncthreads();
    int base = blockIdx.x * CHUNK;
    #pragma unroll 4
    for (int k = 0; k < CHUNK; k += CBLK) {
        int i = base + k + t;
        if (i < E) atomicAdd(&cnt[dst[i] >> SSHIFT], 1);
    }
    __syncthreads();
    for (int s = t; s < NS; s += CBLK) cm[blockIdx.x * NSP + s] = cnt[s];
}

// ---------------------------------------------------------------------------
// passB1: per-stripe exclusive scan over blocks; tot[s] = sum. B <= 256.
// ---------------------------------------------------------------------------
__global__ __launch_bounds__(256) void passB1(int* __restrict__ cm, int* __restrict__ tot,
                                              int B, int NSP) {
    __shared__ int sv[256];
    int t = threadIdx.x, s = blockIdx.x;
    int v = (t < B) ? cm[t * NSP + s] : 0;
    sv[t] = v;
    __syncthreads();
    for (int off = 1; off < 256; off <<= 1) {
        int tmp = (t >= off) ? sv[t - off] : 0;
        __syncthreads();
        sv[t] += tmp;
        __syncthreads();
    }
    if (t < B) cm[t * NSP + s] = sv[t] - v;
    if (t == 255) tot[s] = sv[255];
}

// ---------------------------------------------------------------------------
// passB2: exclusive scan of stripe totals -> stripe base offsets (NS <= 512).
// Also zeroes the dummy row N of h2u (used as zero-pad by agg2 tails).
// ---------------------------------------------------------------------------
__global__ __launch_bounds__(512) void passB2(const int* __restrict__ tot,
                                              int* __restrict__ sbase,
                                              unsigned* __restrict__ h2u_dummy,
                                              int NS) {
    __shared__ int sv[512];
    int t = threadIdx.x;
    int v = (t < NS) ? tot[t] : 0;
    sv[t] = v;
    __syncthreads();
    for (int off = 1; off < 512; off <<= 1) {
        int tmp = (t >= off) ? sv[t - off] : 0;
        __syncthreads();
        sv[t] += tmp;
        __syncthreads();
    }
    if (t < NS) sbase[t] = sv[t] - v;
    if (t >= 504) h2u_dummy[t - 504] = 0u;    // 8 uints = h2u row N
}

// ---------------------------------------------------------------------------
// passC: bucket edges by stripe; LDS cursors; packed (dl<<17)|src
// ---------------------------------------------------------------------------
__global__ __launch_bounds__(CBLK) void passC(const int* __restrict__ src,
                                              const int* __restrict__ dst,
                                              const int* __restrict__ cm,
                                              const int* __restrict__ sbase,
                                              int* __restrict__ eb,
                                              int E, int NS, int NSP) {
    __shared__ int cur[512];
    int t = threadIdx.x, b = blockIdx.x;
    for (int s = t; s < NS; s += CBLK) cur[s] = sbase[s] + cm[b * NSP + s];
    __syncthreads();
    int base = b * CHUNK;
    #pragma unroll 4
    for (int k = 0; k < CHUNK; k += CBLK) {
        int i = base + k + t;
        if (i < E) {
            int d = dst[i];
            int s = d >> SSHIFT;
            int pos = atomicAdd(&cur[s], 1);
            eb[pos] = src[i] | ((d & SMASK) << 17);
        }
    }
}

// ---------------------------------------------------------------------------
// passD: per-stripe LDS counting sort -> exact CSR + row_ptr + dinv.
// ---------------------------------------------------------------------------
__global__ __launch_bounds__(256) void passD(const int* __restrict__ eb,
                                             const int* __restrict__ sbase,
                                             const int* __restrict__ tot,
                                             int* __restrict__ csr_src,
                                             int* __restrict__ row_ptr,
                                             float* __restrict__ dinv,
                                             int N, int E, int NS) {
    __shared__ int deg[128], incl[128], cur[128];
    int s = blockIdx.x, t = threadIdx.x;
    if (t < 128) deg[t] = 0;
    __syncthreads();
    int b0 = sbase[s], cnt = tot[s];
    for (int k = t; k < cnt; k += 256) atomicAdd(&deg[eb[b0 + k] >> 17], 1);
    __syncthreads();
    if (t < 128) incl[t] = deg[t];
    __syncthreads();
    for (int off = 1; off < 128; off <<= 1) {
        int tmp = 0;
        if (t < 128 && t >= off) tmp = incl[t - off];
        __syncthreads();
        if (t < 128) incl[t] += tmp;
        __syncthreads();
    }
    if (t < 128) {
        int loff = incl[t] - deg[t];
        cur[t] = b0 + loff;
        int n = (s << SSHIFT) + t;
        if (n < N) {
            row_ptr[n] = b0 + loff;
            dinv[n] = rsqrtf((float)(deg[t] + 1));
        }
    }
    if (s == NS - 1 && t == 0) row_ptr[N] = E;
    __syncthreads();
    for (int k = t; k < cnt; k += 256) {
        int v = eb[b0 + k];
        int dl = v >> 17;
        int p = atomicAdd(&cur[dl], 1);
        csr_src[p] = v & 0x1FFFF;
    }
}

// ---------------------------------------------------------------------------
// GEMM1: h1 = bf16( (x @ W1) * dinv[n] ), row = 32 uints. Row N = zeros (dummy).
// ---------------------------------------------------------------------------
__global__ __launch_bounds__(256) void gemm1_kernel(const float* __restrict__ x,
                                                    const float* __restrict__ W1,
                                                    const float* __restrict__ dinv,
                                                    unsigned* __restrict__ h1u, int N) {
    __shared__ __align__(16) float sW[IN_DIM * HID_DIM];   // 32 KB
    __shared__ __align__(16) float sx[16 * IN_DIM];        // 8 KB
    int t = threadIdx.x;
    int node0 = blockIdx.x * 16;

    const float4* W4  = (const float4*)W1;
    float4*       sW4 = (float4*)sW;
    for (int i = t; i < (IN_DIM * HID_DIM) / 4; i += 256) sW4[i] = W4[i];

    const float4* x4  = (const float4*)x;
    float4*       sx4 = (float4*)sx;
    for (int i = t; i < (16 * IN_DIM) / 4; i += 256) {
        int r = i >> 5, c = i & 31;
        int n = node0 + r; if (n >= N) n = 0;   // clamp; dummy row gets dn=0
        sx4[(r << 5) + c] = x4[(size_t)n * 32 + c];
    }
    __syncthreads();

    int ln = t >> 4, jj = t & 15;
    int n = node0 + ln;
    float4 acc = {0.f, 0.f, 0.f, 0.f};
    const float* xr = sx + ln * IN_DIM;
    #pragma unroll 4
    for (int k = 0; k < IN_DIM; ++k) {
        float  xk = xr[k];
        float4 wv = ((const float4*)(sW + k * HID_DIM))[jj];
        acc.x += xk * wv.x; acc.y += xk * wv.y; acc.z += xk * wv.z; acc.w += xk * wv.w;
    }
    if (n <= N) {
        float dn = (n < N) ? dinv[n] : 0.f;     // row N -> zeros
        uint2 pv;
        pv.x = packbf2(acc.x * dn, acc.y * dn);
        pv.y = packbf2(acc.z * dn, acc.w * dn);
        ((uint2*)(h1u + (size_t)n * 32))[jj] = pv;
    }
}

// ---------------------------------------------------------------------------
// Fused agg1 + gemm2: one wave per node. lane = (es 0..7, dg 0..7).
// Gather: 4-deep unrolled uint4 loads (32 edge rows in flight); indices via
// one coalesced load + __shfl; extras land on zero dummy row N.
// Epilogue: r = relu(dn*a + b1) fp32, then h2[n][2es,2es+1] = dn*(r @ W2)
// using a PER-LANE REGISTER W2 fragment (rows 8dg..8dg+7, cols 2es,2es+1)
// -- no LDS at all (round-6 LDS layout caused 8-way bank conflicts,
// SQ_LDS_BANK_CONFLICT=1.12e7). h1a never materialized.
// ---------------------------------------------------------------------------
__global__ __launch_bounds__(256) void agg1_kernel(const unsigned* __restrict__ h1u,
                                                   const int* __restrict__ row_ptr,
                                                   const int* __restrict__ csr_src,
                                                   const float* __restrict__ dinv,
                                                   const float* __restrict__ b1,
                                                   const float* __restrict__ W2,
                                                   unsigned* __restrict__ h2u, int N) {
    int t = threadIdx.x;
    int n = blockIdx.x * 4 + (t >> 6);
    if (n >= N) return;
    int lane = t & 63;
    int es = lane >> 3;        // edge slot 0..7  (also output col pair 2es,2es+1)
    int dg = lane & 7;         // dim group: uint4 = dims 8dg..8dg+7

    // W2 fragment in registers (L1/L2-hot 4 KB table, no conflicts)
    float2 wf[8];
    #pragma unroll
    for (int i = 0; i < 8; ++i)
        wf[i] = *(const float2*)(W2 + (8 * dg + i) * OUT_DIM + 2 * es);

    int e0 = row_ptr[n], e1 = row_ptr[n + 1];
    const uint4* rb = (const uint4*)h1u;     // row = 8 uint4

    float a0 = 0.f, a1 = 0.f, a2 = 0.f, a3 = 0.f,
          a4 = 0.f, a5 = 0.f, a6 = 0.f, a7 = 0.f;

    for (int base = e0 - 1; base < e1; base += 64) {
        int idx = base + lane;
        int sld = N;
        if (idx == e0 - 1) sld = n;              // self loop item
        else if (idx < e1) sld = csr_src[idx];   // predicated coalesced load
        int lim = e1 - base;                     // valid items this chunk (>=1)
        int nr = (lim + 7) >> 3;                 // rounds of 8
        nr = (nr + 3) & ~3;                      // multiple of 4 (extras hit row N)
        for (int r = 0; r < nr; r += 4) {
            int sA = __shfl(sld, ((r + 0) << 3) + es);
            int sB = __shfl(sld, ((r + 1) << 3) + es);
            int sC = __shfl(sld, ((r + 2) << 3) + es);
            int sD = __shfl(sld, ((r + 3) << 3) + es);
            uint4 vA = rb[(size_t)sA * 8 + dg];
            uint4 vB = rb[(size_t)sB * 8 + dg];
            uint4 vC = rb[(size_t)sC * 8 + dg];
            uint4 vD = rb[(size_t)sD * 8 + dg];
            a0 += (bflo(vA.x) + bflo(vB.x)) + (bflo(vC.x) + bflo(vD.x));
            a1 += (bfhi(vA.x) + bfhi(vB.x)) + (bfhi(vC.x) + bfhi(vD.x));
            a2 += (bflo(vA.y) + bflo(vB.y)) + (bflo(vC.y) + bflo(vD.y));
            a3 += (bfhi(vA.y) + bfhi(vB.y)) + (bfhi(vC.y) + bfhi(vD.y));
            a4 += (bflo(vA.z) + bflo(vB.z)) + (bflo(vC.z) + bflo(vD.z));
            a5 += (bfhi(vA.z) + bfhi(vB.z)) + (bfhi(vC.z) + bfhi(vD.z));
            a6 += (bflo(vA.w) + bflo(vB.w)) + (bflo(vC.w) + bflo(vD.w));
            a7 += (bfhi(vA.w) + bfhi(vB.w)) + (bfhi(vC.w) + bfhi(vD.w));
        }
    }
    // reduce over edge slots (es stride 8 -> xor 8,16,32); all lanes get sums
    #pragma unroll
    for (int m = 8; m <= 32; m <<= 1) {
        a0 += __shfl_xor(a0, m); a1 += __shfl_xor(a1, m);
        a2 += __shfl_xor(a2, m); a3 += __shfl_xor(a3, m);
        a4 += __shfl_xor(a4, m); a5 += __shfl_xor(a5, m);
        a6 += __shfl_xor(a6, m); a7 += __shfl_xor(a7, m);
    }
    // epilogue on ALL lanes: h1a slice in fp32
    float dn = dinv[n];
    float4 bA = ((const float4*)b1)[2 * dg];
    float4 bB = ((const float4*)b1)[2 * dg + 1];
    float r0 = fmaxf(fmaf(dn, a0, bA.x), 0.f);
    float r1 = fmaxf(fmaf(dn, a1, bA.y), 0.f);
    float r2 = fmaxf(fmaf(dn, a2, bA.z), 0.f);
    float r3 = fmaxf(fmaf(dn, a3, bA.w), 0.f);
    float r4 = fmaxf(fmaf(dn, a4, bB.x), 0.f);
    float r5 = fmaxf(fmaf(dn, a5, bB.y), 0.f);
    float r6 = fmaxf(fmaf(dn, a6, bB.z), 0.f);
    float r7 = fmaxf(fmaf(dn, a7, bB.w), 0.f);

    // fused gemm2: lane (es,dg) partials for cols 2es,2es+1 over dims 8dg..8dg+7
    float p0, p1;
    p0 = r0 * wf[0].x;            p1 = r0 * wf[0].y;
    p0 = fmaf(r1, wf[1].x, p0);   p1 = fmaf(r1, wf[1].y, p1);
    p0 = fmaf(r2, wf[2].x, p0);   p1 = fmaf(r2, wf[2].y, p1);
    p0 = fmaf(r3, wf[3].x, p0);   p1 = fmaf(r3, wf[3].y, p1);
    p0 = fmaf(r4, wf[4].x, p0);   p1 = fmaf(r4, wf[4].y, p1);
    p0 = fmaf(r5, wf[5].x, p0);   p1 = fmaf(r5, wf[5].y, p1);
    p0 = fmaf(r6, wf[6].x, p0);   p1 = fmaf(r6, wf[6].y, p1);
    p0 = fmaf(r7, wf[7].x, p0);   p1 = fmaf(r7, wf[7].y, p1);
    // reduce over dg (low 3 lane bits)
    #pragma unroll
    for (int m = 1; m <= 4; m <<= 1) {
        p0 += __shfl_xor(p0, m);
        p1 += __shfl_xor(p1, m);
    }
    if (dg == 0) {
        // store pre-scaled by dinv[n] for agg2
        h2u[(size_t)n * 8 + es] = packbf2(p0 * dn, p1 * dn);
    }
}

// ---------------------------------------------------------------------------
// Aggregation layer 2: one wave per node. lane = (es 0..15, dg 0..3).
// uint2 per lane (4 bf16 dims) -> one load instruction = 16 edge rows.
// h2u (1.6 MB) is L2-resident. out = dinv[n]*sum + b2, fp32.
// ---------------------------------------------------------------------------
__global__ __launch_bounds__(256) void agg2_kernel(const unsigned* __restrict__ h2u,
                                                   const int* __restrict__ row_ptr,
                                                   const int* __restrict__ csr_src,
                                                   const float* __restrict__ dinv,
                                                   const float* __restrict__ b2,
                                                   float* __restrict__ out, int N) {
    int t = threadIdx.x;
    int n = blockIdx.x * 4 + (t >> 6);
    if (n >= N) return;
    int lane = t & 63;
    int es = lane >> 2;        // edge slot 0..15
    int dg = lane & 3;         // dim group: uint2 = dims 4dg..4dg+3

    int e0 = row_ptr[n], e1 = row_ptr[n + 1];
    const uint2* rb = (const uint2*)h2u;     // row = 4 uint2

    float a0 = 0.f, a1 = 0.f, a2 = 0.f, a3 = 0.f;

    for (int base = e0 - 1; base < e1; base += 64) {
        int idx = base + lane;
        int sld = N;
        if (idx == e0 - 1) sld = n;
        else if (idx < e1) sld = csr_src[idx];
        int lim = e1 - base;
        int nr = (lim + 15) >> 4;                // rounds of 16
        nr = (nr + 1) & ~1;                      // even (extras hit row N)
        for (int r = 0; r < nr; r += 2) {
            int sA = __shfl(sld, (r << 4) + es);
            int sB = __shfl(sld, ((r + 1) << 4) + es);
            uint2 vA = rb[(size_t)sA * 4 + dg];
            uint2 vB = rb[(size_t)sB * 4 + dg];
            a0 += bflo(vA.x) + bflo(vB.x);
            a1 += bfhi(vA.x) + bfhi(vB.x);
            a2 += bflo(vA.y) + bflo(vB.y);
            a3 += bfhi(vA.y) + bfhi(vB.y);
        }
    }
    // reduce over edge slots (es stride 4 -> xor 4,8,16,32)
    #pragma unroll
    for (int m = 4; m <= 32; m <<= 1) {
        a0 += __shfl_xor(a0, m); a1 += __shfl_xor(a1, m);
        a2 += __shfl_xor(a2, m); a3 += __shfl_xor(a3, m);
    }
    if (es == 0) {
        float dn = dinv[n];
        float4 bb = ((const float4*)b2)[dg];
        float4 r;
        r.x = fmaf(dn, a0, bb.x);
        r.y = fmaf(dn, a1, bb.y);
        r.z = fmaf(dn, a2, bb.z);
        r.w = fmaf(dn, a3, bb.w);
        ((float4*)out)[(size_t)n * 4 + dg] = r;
    }
}

// ---------------------------------------------------------------------------
// Launch
// ---------------------------------------------------------------------------
extern "C" void kernel_launch(void* const* d_in, const int* in_sizes, int n_in,
                              void* d_out, int out_size, void* d_ws, size_t ws_size,
                              hipStream_t stream) {
    const float* x  = (const float*)d_in[0];
    const int*   ei = (const int*)d_in[1];
    const float* W1 = (const float*)d_in[2];
    const float* b1 = (const float*)d_in[3];
    const float* W2 = (const float*)d_in[4];
    const float* b2 = (const float*)d_in[5];
    float* out = (float*)d_out;

    const int N = in_sizes[0] / IN_DIM;   // 50000
    const int E = in_sizes[1] / 2;        // 1000000
    const int* src = ei;
    const int* dst = ei + E;

    const int NS  = (N + SMASK) >> SSHIFT;       // 391 stripes
    const int NSP = NS + 1;
    const int BC  = (E + CHUNK - 1) / CHUNK;     // 245 chunks (<= 256)

    char* w = (char*)d_ws;
    auto alloc = [&](size_t bytes) -> void* {
        void* p = (void*)w;
        w += (bytes + 255) & ~(size_t)255;
        return p;
    };
    int*      cm      = (int*)     alloc((size_t)256 * NSP * 4);
    int*      tot     = (int*)     alloc((size_t)NS * 4);
    int*      sbase   = (int*)     alloc((size_t)NS * 4);
    int*      eb      = (int*)     alloc((size_t)E * 4);
    int*      csr_src = (int*)     alloc((size_t)E * 4);
    int*      row_ptr = (int*)     alloc((size_t)(N + 1) * 4);
    float*    dinv    = (float*)   alloc((size_t)N * 4);
    unsigned* h1u     = (unsigned*)alloc((size_t)(N + 1) * 32 * 4);  // bf16 [N+1][64]
    unsigned* h2u     = (unsigned*)alloc((size_t)(N + 1) * 8 * 4);   // bf16 [N+1][16]

    const int GB = (N + 16) / 16;    // covers rows 0..N (incl. dummy)
    const int AB = (N + 3) / 4;      // 4 nodes (waves) per block

    passA <<<BC, CBLK, 0, stream>>>(dst, cm, E, NS, NSP);
    passB1<<<NS, 256,  0, stream>>>(cm, tot, BC, NSP);
    passB2<<<1,  512,  0, stream>>>(tot, sbase, h2u + (size_t)N * 8, NS);
    passC <<<BC, CBLK, 0, stream>>>(src, dst, cm, sbase, eb, E, NS, NSP);
    passD <<<NS, 256,  0, stream>>>(eb, sbase, tot, csr_src, row_ptr, dinv, N, E, NS);

    gemm1_kernel<<<GB, 256, 0, stream>>>(x, W1, dinv, h1u, N);
    agg1_kernel<<<AB, 256, 0, stream>>>(h1u, row_ptr, csr_src, dinv, b1, W2, h2u, N);
    agg2_kernel<<<AB, 256, 0, stream>>>(h2u, row_ptr, csr_src, dinv, b2, out, N);
}

// Round 8
// 186.322 us; speedup vs baseline: 1.1262x; 1.1262x over previous
//
#include <hip/hip_runtime.h>
#include <hip/hip_bf16.h>

#define IN_DIM 128
#define HID_DIM 64
#define OUT_DIM 16

// Stripe/bin geometry: 128 nodes per stripe
#define SSHIFT 7
#define SMASK 127
// Edge chunking for passes A/C: 245 blocks -> all CUs busy
#define CHUNK 4096
#define CBLK 256

// bf16 helpers: round-to-nearest-even pack, bit-shift unpack
static __device__ __forceinline__ unsigned short f2bf(float f) {
    unsigned u = __float_as_uint(f);
    unsigned r = u + 0x7fffu + ((u >> 16) & 1u);
    return (unsigned short)(r >> 16);
}
static __device__ __forceinline__ unsigned packbf2(float a, float b) {
    return (unsigned)f2bf(a) | ((unsigned)f2bf(b) << 16);
}
static __device__ __forceinline__ float bflo(unsigned v) { return __uint_as_float(v << 16); }
static __device__ __forceinline__ float bfhi(unsigned v) { return __uint_as_float(v & 0xffff0000u); }

// ---------------------------------------------------------------------------
// passA: per-block per-stripe histogram (LDS only, no global atomics)
// ---------------------------------------------------------------------------
__global__ __launch_bounds__(CBLK) void passA(const int* __restrict__ dst,
                                              int* __restrict__ cm,
                                              int E, int NS, int NSP) {
    __shared__ int cnt[512];
    int t = threadIdx.x;
    for (int s = t; s < NS; s += CBLK) cnt[s] = 0;
    __syncthreads();
    int base = blockIdx.x * CHUNK;
    #pragma unroll 4
    for (int k = 0; k < CHUNK; k += CBLK) {
        int i = base + k + t;
        if (i < E) atomicAdd(&cnt[dst[i] >> SSHIFT], 1);
    }
    __syncthreads();
    for (int s = t; s < NS; s += CBLK) cm[blockIdx.x * NSP + s] = cnt[s];
}

// ---------------------------------------------------------------------------
// passB1: per-stripe exclusive scan over blocks; tot[s] = sum. B <= 256.
// ---------------------------------------------------------------------------
__global__ __launch_bounds__(256) void passB1(int* __restrict__ cm, int* __restrict__ tot,
                                              int B, int NSP) {
    __shared__ int sv[256];
    int t = threadIdx.x, s = blockIdx.x;
    int v = (t < B) ? cm[t * NSP + s] : 0;
    sv[t] = v;
    __syncthreads();
    for (int off = 1; off < 256; off <<= 1) {
        int tmp = (t >= off) ? sv[t - off] : 0;
        __syncthreads();
        sv[t] += tmp;
        __syncthreads();
    }
    if (t < B) cm[t * NSP + s] = sv[t] - v;
    if (t == 255) tot[s] = sv[255];
}

// ---------------------------------------------------------------------------
// passC: bucket edges by stripe; LDS cursors; packed (dl<<17)|src.
// Computes sbase (exclusive scan of tot, NS<=512) inline in LDS: 256 threads
// handle 2 elements each, Hillis-Steele (read-all then write-all per step).
// ---------------------------------------------------------------------------
__global__ __launch_bounds__(CBLK) void passC(const int* __restrict__ src,
                                              const int* __restrict__ dst,
                                              const int* __restrict__ cm,
                                              const int* __restrict__ tot,
                                              int* __restrict__ eb,
                                              int E, int NS, int NSP) {
    __shared__ int sb[512];
    __shared__ int cur[512];
    int t = threadIdx.x, b = blockIdx.x;
    int i0 = t, i1 = t + 256;
    int v0 = (i0 < NS) ? tot[i0] : 0;
    int v1 = (i1 < NS) ? tot[i1] : 0;
    sb[i0] = v0; sb[i1] = v1;
    __syncthreads();
    for (int off = 1; off < 512; off <<= 1) {
        int t0 = (i0 >= off) ? sb[i0 - off] : 0;
        int t1 = (i1 >= off) ? sb[i1 - off] : 0;
        __syncthreads();
        sb[i0] += t0; sb[i1] += t1;
        __syncthreads();
    }
    // inclusive -> exclusive, add per-block offset
    if (i0 < NS) cur[i0] = (sb[i0] - v0) + cm[b * NSP + i0];
    if (i1 < NS) cur[i1] = (sb[i1] - v1) + cm[b * NSP + i1];
    __syncthreads();
    int base = b * CHUNK;
    #pragma unroll 4
    for (int k = 0; k < CHUNK; k += CBLK) {
        int i = base + k + t;
        if (i < E) {
            int d = dst[i];
            int s = d >> SSHIFT;
            int pos = atomicAdd(&cur[s], 1);
            eb[pos] = src[i] | ((d & SMASK) << 17);
        }
    }
}

// ---------------------------------------------------------------------------
// passD: per-stripe LDS counting sort -> exact CSR + row_ptr + dinv.
// Computes b0 = sbase[s] = sum(tot[0..s)) by block reduction (L2-hot tot).
// ---------------------------------------------------------------------------
__global__ __launch_bounds__(256) void passD(const int* __restrict__ eb,
                                             const int* __restrict__ tot,
                                             int* __restrict__ csr_src,
                                             int* __restrict__ row_ptr,
                                             float* __restrict__ dinv,
                                             int N, int E, int NS) {
    __shared__ int red[256];
    __shared__ int deg[128], incl[128], cur[128];
    int s = blockIdx.x, t = threadIdx.x;
    if (t < 128) deg[t] = 0;
    int part = 0;
    for (int k = t; k < s; k += 256) part += tot[k];
    red[t] = part;
    __syncthreads();
    for (int off = 128; off >= 1; off >>= 1) {
        if (t < off) red[t] += red[t + off];
        __syncthreads();
    }
    int b0 = red[0];
    int cnt = tot[s];
    for (int k = t; k < cnt; k += 256) atomicAdd(&deg[eb[b0 + k] >> 17], 1);
    __syncthreads();
    if (t < 128) incl[t] = deg[t];
    __syncthreads();
    for (int off = 1; off < 128; off <<= 1) {
        int tmp = 0;
        if (t < 128 && t >= off) tmp = incl[t - off];
        __syncthreads();
        if (t < 128) incl[t] += tmp;
        __syncthreads();
    }
    if (t < 128) {
        int loff = incl[t] - deg[t];
        cur[t] = b0 + loff;
        int n = (s << SSHIFT) + t;
        if (n < N) {
            row_ptr[n] = b0 + loff;
            dinv[n] = rsqrtf((float)(deg[t] + 1));
        }
    }
    if (s == NS - 1 && t == 0) row_ptr[N] = E;
    __syncthreads();
    for (int k = t; k < cnt; k += 256) {
        int v = eb[b0 + k];
        int dl = v >> 17;
        int p = atomicAdd(&cur[dl], 1);
        csr_src[p] = v & 0x1FFFF;
    }
}

// ---------------------------------------------------------------------------
// GEMM1: h1 = bf16( (x @ W1) * dinv[n] ), row = 32 uints. Row N = zeros (dummy).
// ---------------------------------------------------------------------------
__global__ __launch_bounds__(256) void gemm1_kernel(const float* __restrict__ x,
                                                    const float* __restrict__ W1,
                                                    const float* __restrict__ dinv,
                                                    unsigned* __restrict__ h1u, int N) {
    __shared__ __align__(16) float sW[IN_DIM * HID_DIM];   // 32 KB
    __shared__ __align__(16) float sx[16 * IN_DIM];        // 8 KB
    int t = threadIdx.x;
    int node0 = blockIdx.x * 16;

    const float4* W4  = (const float4*)W1;
    float4*       sW4 = (float4*)sW;
    for (int i = t; i < (IN_DIM * HID_DIM) / 4; i += 256) sW4[i] = W4[i];

    const float4* x4  = (const float4*)x;
    float4*       sx4 = (float4*)sx;
    for (int i = t; i < (16 * IN_DIM) / 4; i += 256) {
        int r = i >> 5, c = i & 31;
        int n = node0 + r; if (n >= N) n = 0;   // clamp; dummy row gets dn=0
        sx4[(r << 5) + c] = x4[(size_t)n * 32 + c];
    }
    __syncthreads();

    int ln = t >> 4, jj = t & 15;
    int n = node0 + ln;
    float4 acc = {0.f, 0.f, 0.f, 0.f};
    const float* xr = sx + ln * IN_DIM;
    #pragma unroll 4
    for (int k = 0; k < IN_DIM; ++k) {
        float  xk = xr[k];
        float4 wv = ((const float4*)(sW + k * HID_DIM))[jj];
        acc.x += xk * wv.x; acc.y += xk * wv.y; acc.z += xk * wv.z; acc.w += xk * wv.w;
    }
    if (n <= N) {
        float dn = (n < N) ? dinv[n] : 0.f;     // row N -> zeros
        uint2 pv;
        pv.x = packbf2(acc.x * dn, acc.y * dn);
        pv.y = packbf2(acc.z * dn, acc.w * dn);
        ((uint2*)(h1u + (size_t)n * 32))[jj] = pv;
    }
}

// ---------------------------------------------------------------------------
// Aggregation layer 1 (round-5 proven version): one wave per node.
// lane = (es 0..7, dg 0..7); uint4/lane -> one dwordx4 = 8 edge rows (1 KB).
// Indices via one coalesced load + __shfl. 2-deep unroll.
// out = relu( dinv[n]*(h1[n] + sum h1[src]) + b1 ), bf16.
// ---------------------------------------------------------------------------
__global__ __launch_bounds__(256) void agg1_kernel(const unsigned* __restrict__ h1u,
                                                   const int* __restrict__ row_ptr,
                                                   const int* __restrict__ csr_src,
                                                   const float* __restrict__ dinv,
                                                   const float* __restrict__ b1,
                                                   unsigned* __restrict__ h1au, int N) {
    int t = threadIdx.x;
    int n = blockIdx.x * 4 + (t >> 6);
    if (n >= N) return;
    int lane = t & 63;
    int es = lane >> 3;        // edge slot 0..7
    int dg = lane & 7;         // dim group: uint4 = dims 8dg..8dg+7

    int e0 = row_ptr[n], e1 = row_ptr[n + 1];
    const uint4* rb = (const uint4*)h1u;     // row = 8 uint4

    float a0 = 0.f, a1 = 0.f, a2 = 0.f, a3 = 0.f,
          a4 = 0.f, a5 = 0.f, a6 = 0.f, a7 = 0.f;

    for (int base = e0 - 1; base < e1; base += 64) {
        int idx = base + lane;
        int sld = N;
        if (idx == e0 - 1) sld = n;              // self loop item
        else if (idx < e1) sld = csr_src[idx];   // predicated coalesced load
        int lim = e1 - base;                     // valid items this chunk (>=1)
        int nr = (lim + 7) >> 3;                 // rounds of 8
        nr = (nr + 1) & ~1;                      // even # rounds (extras hit row N)
        for (int r = 0; r < nr; r += 2) {
            int sA = __shfl(sld, (r << 3) + es);
            int sB = __shfl(sld, ((r + 1) << 3) + es);
            uint4 vA = rb[(size_t)sA * 8 + dg];
            uint4 vB = rb[(size_t)sB * 8 + dg];
            a0 += bflo(vA.x) + bflo(vB.x);
            a1 += bfhi(vA.x) + bfhi(vB.x);
            a2 += bflo(vA.y) + bflo(vB.y);
            a3 += bfhi(vA.y) + bfhi(vB.y);
            a4 += bflo(vA.z) + bflo(vB.z);
            a5 += bfhi(vA.z) + bfhi(vB.z);
            a6 += bflo(vA.w) + bflo(vB.w);
            a7 += bfhi(vA.w) + bfhi(vB.w);
        }
    }
    // reduce over edge slots (es stride 8 -> xor 8,16,32)
    #pragma unroll
    for (int m = 8; m <= 32; m <<= 1) {
        a0 += __shfl_xor(a0, m); a1 += __shfl_xor(a1, m);
        a2 += __shfl_xor(a2, m); a3 += __shfl_xor(a3, m);
        a4 += __shfl_xor(a4, m); a5 += __shfl_xor(a5, m);
        a6 += __shfl_xor(a6, m); a7 += __shfl_xor(a7, m);
    }
    if (es == 0) {
        float dn = dinv[n];
        float4 bA = ((const float4*)b1)[2 * dg];
        float4 bB = ((const float4*)b1)[2 * dg + 1];
        float r0 = fmaxf(fmaf(dn, a0, bA.x), 0.f);
        float r1 = fmaxf(fmaf(dn, a1, bA.y), 0.f);
        float r2 = fmaxf(fmaf(dn, a2, bA.z), 0.f);
        float r3 = fmaxf(fmaf(dn, a3, bA.w), 0.f);
        float r4 = fmaxf(fmaf(dn, a4, bB.x), 0.f);
        float r5 = fmaxf(fmaf(dn, a5, bB.y), 0.f);
        float r6 = fmaxf(fmaf(dn, a6, bB.z), 0.f);
        float r7 = fmaxf(fmaf(dn, a7, bB.w), 0.f);
        uint4 pv;
        pv.x = packbf2(r0, r1); pv.y = packbf2(r2, r3);
        pv.z = packbf2(r4, r5); pv.w = packbf2(r6, r7);
        ((uint4*)h1au)[(size_t)n * 8 + dg] = pv;
    }
}

// ---------------------------------------------------------------------------
// GEMM2: h2 = bf16( (h1a @ W2) * dinv[n] ), row = 8 uints. Row N = zeros.
// ---------------------------------------------------------------------------
__global__ __launch_bounds__(256) void gemm2_kernel(const unsigned* __restrict__ h1au,
                                                    const float* __restrict__ W2,
                                                    const float* __restrict__ dinv,
                                                    unsigned* __restrict__ h2u, int N) {
    __shared__ __align__(16) float sW[HID_DIM * OUT_DIM];  // 4 KB
    __shared__ __align__(16) float sx[16 * HID_DIM];       // 4 KB
    int t = threadIdx.x;
    int node0 = blockIdx.x * 16;

    ((float4*)sW)[t] = ((const float4*)W2)[t];
    for (int i = t; i < 512; i += 256) {           // 16 rows x 32 uints
        int r = i >> 5, c = i & 31;
        int n = node0 + r; if (n >= N) n = 0;      // clamp; dummy handled by dn=0
        unsigned v = h1au[(size_t)n * 32 + c];
        float2 f; f.x = bflo(v); f.y = bfhi(v);
        *(float2*)(sx + r * HID_DIM + 2 * c) = f;
    }
    __syncthreads();

    int ln = t >> 4, j = t & 15;
    float acc = 0.f;
    const float* xr = sx + ln * HID_DIM;
    #pragma unroll 8
    for (int k = 0; k < HID_DIM; ++k) acc += xr[k] * sW[k * OUT_DIM + j];
    int n = node0 + ln;
    float other = __shfl_xor(acc, 1);              // pair dims (j even, j odd)
    if (n <= N && (j & 1) == 0) {
        float dn = (n < N) ? dinv[n] : 0.f;        // row N -> zeros (agg2 zero-pad)
        h2u[(size_t)n * 8 + (j >> 1)] = packbf2(acc * dn, other * dn);
    }
}

// ---------------------------------------------------------------------------
// Aggregation layer 2 (round-5 proven version): one wave per node.
// lane = (es 0..15, dg 0..3); uint2/lane -> one load = 16 edge rows.
// h2u (1.6 MB) is L2-resident. out = dinv[n]*sum + b2, fp32.
// ---------------------------------------------------------------------------
__global__ __launch_bounds__(256) void agg2_kernel(const unsigned* __restrict__ h2u,
                                                   const int* __restrict__ row_ptr,
                                                   const int* __restrict__ csr_src,
                                                   const float* __restrict__ dinv,
                                                   const float* __restrict__ b2,
                                                   float* __restrict__ out, int N) {
    int t = threadIdx.x;
    int n = blockIdx.x * 4 + (t >> 6);
    if (n >= N) return;
    int lane = t & 63;
    int es = lane >> 2;        // edge slot 0..15
    int dg = lane & 3;         // dim group: uint2 = dims 4dg..4dg+3

    int e0 = row_ptr[n], e1 = row_ptr[n + 1];
    const uint2* rb = (const uint2*)h2u;     // row = 4 uint2

    float a0 = 0.f, a1 = 0.f, a2 = 0.f, a3 = 0.f;

    for (int base = e0 - 1; base < e1; base += 64) {
        int idx = base + lane;
        int sld = N;
        if (idx == e0 - 1) sld = n;
        else if (idx < e1) sld = csr_src[idx];
        int lim = e1 - base;
        int nr = (lim + 15) >> 4;                // rounds of 16
        nr = (nr + 1) & ~1;                      // even (extras hit row N)
        for (int r = 0; r < nr; r += 2) {
            int sA = __shfl(sld, (r << 4) + es);
            int sB = __shfl(sld, ((r + 1) << 4) + es);
            uint2 vA = rb[(size_t)sA * 4 + dg];
            uint2 vB = rb[(size_t)sB * 4 + dg];
            a0 += bflo(vA.x) + bflo(vB.x);
            a1 += bfhi(vA.x) + bfhi(vB.x);
            a2 += bflo(vA.y) + bflo(vB.y);
            a3 += bfhi(vA.y) + bfhi(vB.y);
        }
    }
    // reduce over edge slots (es stride 4 -> xor 4,8,16,32)
    #pragma unroll
    for (int m = 4; m <= 32; m <<= 1) {
        a0 += __shfl_xor(a0, m); a1 += __shfl_xor(a1, m);
        a2 += __shfl_xor(a2, m); a3 += __shfl_xor(a3, m);
    }
    if (es == 0) {
        float dn = dinv[n];
        float4 bb = ((const float4*)b2)[dg];
        float4 r;
        r.x = fmaf(dn, a0, bb.x);
        r.y = fmaf(dn, a1, bb.y);
        r.z = fmaf(dn, a2, bb.z);
        r.w = fmaf(dn, a3, bb.w);
        ((float4*)out)[(size_t)n * 4 + dg] = r;
    }
}

// ---------------------------------------------------------------------------
// Launch
// ---------------------------------------------------------------------------
extern "C" void kernel_launch(void* const* d_in, const int* in_sizes, int n_in,
                              void* d_out, int out_size, void* d_ws, size_t ws_size,
                              hipStream_t stream) {
    const float* x  = (const float*)d_in[0];
    const int*   ei = (const int*)d_in[1];
    const float* W1 = (const float*)d_in[2];
    const float* b1 = (const float*)d_in[3];
    const float* W2 = (const float*)d_in[4];
    const float* b2 = (const float*)d_in[5];
    float* out = (float*)d_out;

    const int N = in_sizes[0] / IN_DIM;   // 50000
    const int E = in_sizes[1] / 2;        // 1000000
    const int* src = ei;
    const int* dst = ei + E;

    const int NS  = (N + SMASK) >> SSHIFT;       // 391 stripes (<= 512)
    const int NSP = NS + 1;
    const int BC  = (E + CHUNK - 1) / CHUNK;     // 245 chunks (<= 256)

    char* w = (char*)d_ws;
    auto alloc = [&](size_t bytes) -> void* {
        void* p = (void*)w;
        w += (bytes + 255) & ~(size_t)255;
        return p;
    };
    int*      cm      = (int*)     alloc((size_t)256 * NSP * 4);
    int*      tot     = (int*)     alloc((size_t)NS * 4);
    int*      eb      = (int*)     alloc((size_t)E * 4);
    int*      csr_src = (int*)     alloc((size_t)E * 4);
    int*      row_ptr = (int*)     alloc((size_t)(N + 1) * 4);
    float*    dinv    = (float*)   alloc((size_t)N * 4);
    unsigned* h1u     = (unsigned*)alloc((size_t)(N + 1) * 32 * 4);  // bf16 [N+1][64]
    unsigned* h1au    = (unsigned*)alloc((size_t)(N + 1) * 32 * 4);
    unsigned* h2u     = (unsigned*)alloc((size_t)(N + 1) * 8 * 4);   // bf16 [N+1][16]

    const int GB = (N + 16) / 16;    // covers rows 0..N (incl. dummy)
    const int AB = (N + 3) / 4;      // 4 nodes (waves) per block

    passA <<<BC, CBLK, 0, stream>>>(dst, cm, E, NS, NSP);
    passB1<<<NS, 256,  0, stream>>>(cm, tot, BC, NSP);
    passC <<<BC, CBLK, 0, stream>>>(src, dst, cm, tot, eb, E, NS, NSP);
    passD <<<NS, 256,  0, stream>>>(eb, tot, csr_src, row_ptr, dinv, N, E, NS);

    gemm1_kernel<<<GB, 256, 0, stream>>>(x, W1, dinv, h1u, N);
    agg1_kernel<<<AB, 256, 0, stream>>>(h1u, row_ptr, csr_src, dinv, b1, h1au, N);
    gemm2_kernel<<<GB, 256, 0, stream>>>(h1au, W2, dinv, h2u, N);
    agg2_kernel<<<AB, 256, 0, stream>>>(h2u, row_ptr, csr_src, dinv, b2, out, N);
}

// Round 9
// 172.023 us; speedup vs baseline: 1.2198x; 1.0831x over previous
//
#include <hip/hip_runtime.h>
#include <hip/hip_bf16.h>

#define IN_DIM 128
#define HID_DIM 64
#define OUT_DIM 16

// Stripe/bin geometry: 128 nodes per stripe
#define SSHIFT 7
#define SMASK 127
// Edge chunking for passes A/C: 245 blocks -> all CUs busy
#define CHUNK 4096
#define CBLK 256

// bf16 helpers: round-to-nearest-even pack, bit-shift unpack
static __device__ __forceinline__ unsigned short f2bf(float f) {
    unsigned u = __float_as_uint(f);
    unsigned r = u + 0x7fffu + ((u >> 16) & 1u);
    return (unsigned short)(r >> 16);
}
static __device__ __forceinline__ unsigned packbf2(float a, float b) {
    return (unsigned)f2bf(a) | ((unsigned)f2bf(b) << 16);
}
static __device__ __forceinline__ float bflo(unsigned v) { return __uint_as_float(v << 16); }
static __device__ __forceinline__ float bfhi(unsigned v) { return __uint_as_float(v & 0xffff0000u); }

// ---------------------------------------------------------------------------
// passA: per-block per-stripe histogram (LDS only, no global atomics)
// ---------------------------------------------------------------------------
__global__ __launch_bounds__(CBLK) void passA(const int* __restrict__ dst,
                                              int* __restrict__ cm,
                                              int E, int NS, int NSP) {
    __shared__ int cnt[512];
    int t = threadIdx.x;
    for (int s = t; s < NS; s += CBLK) cnt[s] = 0;
    __syncthreads();
    int base = blockIdx.x * CHUNK;
    #pragma unroll 4
    for (int k = 0; k < CHUNK; k += CBLK) {
        int i = base + k + t;
        if (i < E) atomicAdd(&cnt[dst[i] >> SSHIFT], 1);
    }
    __syncthreads();
    for (int s = t; s < NS; s += CBLK) cm[blockIdx.x * NSP + s] = cnt[s];
}

// ---------------------------------------------------------------------------
// passB1: per-stripe exclusive scan over blocks; tot[s] = sum. B <= 256.
// ---------------------------------------------------------------------------
__global__ __launch_bounds__(256) void passB1(int* __restrict__ cm, int* __restrict__ tot,
                                              int B, int NSP) {
    __shared__ int sv[256];
    int t = threadIdx.x, s = blockIdx.x;
    int v = (t < B) ? cm[t * NSP + s] : 0;
    sv[t] = v;
    __syncthreads();
    for (int off = 1; off < 256; off <<= 1) {
        int tmp = (t >= off) ? sv[t - off] : 0;
        __syncthreads();
        sv[t] += tmp;
        __syncthreads();
    }
    if (t < B) cm[t * NSP + s] = sv[t] - v;
    if (t == 255) tot[s] = sv[255];
}

// ---------------------------------------------------------------------------
// passC: bucket edges by stripe; LDS cursors; packed (dl<<17)|src.
// Computes sbase (exclusive scan of tot, NS<=512) inline in LDS.
// ---------------------------------------------------------------------------
__global__ __launch_bounds__(CBLK) void passC(const int* __restrict__ src,
                                              const int* __restrict__ dst,
                                              const int* __restrict__ cm,
                                              const int* __restrict__ tot,
                                              int* __restrict__ eb,
                                              int E, int NS, int NSP) {
    __shared__ int sb[512];
    __shared__ int cur[512];
    int t = threadIdx.x, b = blockIdx.x;
    int i0 = t, i1 = t + 256;
    int v0 = (i0 < NS) ? tot[i0] : 0;
    int v1 = (i1 < NS) ? tot[i1] : 0;
    sb[i0] = v0; sb[i1] = v1;
    __syncthreads();
    for (int off = 1; off < 512; off <<= 1) {
        int t0 = (i0 >= off) ? sb[i0 - off] : 0;
        int t1 = (i1 >= off) ? sb[i1 - off] : 0;
        __syncthreads();
        sb[i0] += t0; sb[i1] += t1;
        __syncthreads();
    }
    if (i0 < NS) cur[i0] = (sb[i0] - v0) + cm[b * NSP + i0];
    if (i1 < NS) cur[i1] = (sb[i1] - v1) + cm[b * NSP + i1];
    __syncthreads();
    int base = b * CHUNK;
    #pragma unroll 4
    for (int k = 0; k < CHUNK; k += CBLK) {
        int i = base + k + t;
        if (i < E) {
            int d = dst[i];
            int s = d >> SSHIFT;
            int pos = atomicAdd(&cur[s], 1);
            eb[pos] = src[i] | ((d & SMASK) << 17);
        }
    }
}

// ---------------------------------------------------------------------------
// passD: per-stripe LDS counting sort -> exact CSR + row_ptr + dinv.
// ---------------------------------------------------------------------------
__global__ __launch_bounds__(256) void passD(const int* __restrict__ eb,
                                             const int* __restrict__ tot,
                                             int* __restrict__ csr_src,
                                             int* __restrict__ row_ptr,
                                             float* __restrict__ dinv,
                                             int N, int E, int NS) {
    __shared__ int red[256];
    __shared__ int deg[128], incl[128], cur[128];
    int s = blockIdx.x, t = threadIdx.x;
    if (t < 128) deg[t] = 0;
    int part = 0;
    for (int k = t; k < s; k += 256) part += tot[k];
    red[t] = part;
    __syncthreads();
    for (int off = 128; off >= 1; off >>= 1) {
        if (t < off) red[t] += red[t + off];
        __syncthreads();
    }
    int b0 = red[0];
    int cnt = tot[s];
    for (int k = t; k < cnt; k += 256) atomicAdd(&deg[eb[b0 + k] >> 17], 1);
    __syncthreads();
    if (t < 128) incl[t] = deg[t];
    __syncthreads();
    for (int off = 1; off < 128; off <<= 1) {
        int tmp = 0;
        if (t < 128 && t >= off) tmp = incl[t - off];
        __syncthreads();
        if (t < 128) incl[t] += tmp;
        __syncthreads();
    }
    if (t < 128) {
        int loff = incl[t] - deg[t];
        cur[t] = b0 + loff;
        int n = (s << SSHIFT) + t;
        if (n < N) {
            row_ptr[n] = b0 + loff;
            dinv[n] = rsqrtf((float)(deg[t] + 1));
        }
    }
    if (s == NS - 1 && t == 0) row_ptr[N] = E;
    __syncthreads();
    for (int k = t; k < cnt; k += 256) {
        int v = eb[b0 + k];
        int dl = v >> 17;
        int p = atomicAdd(&cur[dl], 1);
        csr_src[p] = v & 0x1FFFF;
    }
}

// ---------------------------------------------------------------------------
// GEMM1: h1 = bf16( (x @ W1) * dinv[n] ), row = 32 uints. Row N = zeros (dummy).
// ---------------------------------------------------------------------------
__global__ __launch_bounds__(256) void gemm1_kernel(const float* __restrict__ x,
                                                    const float* __restrict__ W1,
                                                    const float* __restrict__ dinv,
                                                    unsigned* __restrict__ h1u, int N) {
    __shared__ __align__(16) float sW[IN_DIM * HID_DIM];   // 32 KB
    __shared__ __align__(16) float sx[16 * IN_DIM];        // 8 KB
    int t = threadIdx.x;
    int node0 = blockIdx.x * 16;

    const float4* W4  = (const float4*)W1;
    float4*       sW4 = (float4*)sW;
    for (int i = t; i < (IN_DIM * HID_DIM) / 4; i += 256) sW4[i] = W4[i];

    const float4* x4  = (const float4*)x;
    float4*       sx4 = (float4*)sx;
    for (int i = t; i < (16 * IN_DIM) / 4; i += 256) {
        int r = i >> 5, c = i & 31;
        int n = node0 + r; if (n >= N) n = 0;   // clamp; dummy row gets dn=0
        sx4[(r << 5) + c] = x4[(size_t)n * 32 + c];
    }
    __syncthreads();

    int ln = t >> 4, jj = t & 15;
    int n = node0 + ln;
    float4 acc = {0.f, 0.f, 0.f, 0.f};
    const float* xr = sx + ln * IN_DIM;
    #pragma unroll 4
    for (int k = 0; k < IN_DIM; ++k) {
        float  xk = xr[k];
        float4 wv = ((const float4*)(sW + k * HID_DIM))[jj];
        acc.x += xk * wv.x; acc.y += xk * wv.y; acc.z += xk * wv.z; acc.w += xk * wv.w;
    }
    if (n <= N) {
        float dn = (n < N) ? dinv[n] : 0.f;     // row N -> zeros
        uint2 pv;
        pv.x = packbf2(acc.x * dn, acc.y * dn);
        pv.y = packbf2(acc.z * dn, acc.w * dn);
        ((uint2*)(h1u + (size_t)n * 32))[jj] = pv;
    }
}

// ---------------------------------------------------------------------------
// Aggregation layer 1 (v4): TWO nodes per wave (half = node). lane =
// (h 1b, es 0..3, dg 0..7). uint4/lane -> one dwordx4 still fetches 8 edge
// rows (4 per node) but every wave instruction is amortized over 2 nodes:
// loads 4->3/node, reduce 3->2 xor levels (both nodes reduced at once).
// Indices: 32 consecutive per half via one predicated load + __shfl.
// out = relu( dinv[n]*(h1[n] + sum h1[src]) + b1 ), bf16.
// ---------------------------------------------------------------------------
__global__ __launch_bounds__(256) void agg1_kernel(const unsigned* __restrict__ h1u,
                                                   const int* __restrict__ row_ptr,
                                                   const int* __restrict__ csr_src,
                                                   const float* __restrict__ dinv,
                                                   const float* __restrict__ b1,
                                                   unsigned* __restrict__ h1au, int N) {
    int t = threadIdx.x;
    int lane = t & 63;
    int h  = lane >> 5;            // node half 0/1
    int l  = lane & 31;
    int es = l >> 3;               // edge slot 0..3
    int dg = l & 7;                // dim group: uint4 = dims 8dg..8dg+7
    int n = blockIdx.x * 8 + ((t >> 6) << 1) + h;   // 2 nodes/wave, 8/block
    if (n >= N) return;

    int e0 = row_ptr[n], e1 = row_ptr[n + 1];
    const uint4* rb = (const uint4*)h1u;     // row = 8 uint4
    int sb = h << 5;                          // shfl base for this half

    float a0 = 0.f, a1 = 0.f, a2 = 0.f, a3 = 0.f,
          a4 = 0.f, a5 = 0.f, a6 = 0.f, a7 = 0.f;

    for (int base = e0 - 1; base < e1; base += 32) {
        int idx = base + l;
        int sld = N;
        if (idx == e0 - 1) sld = n;              // self loop item
        else if (idx < e1) sld = csr_src[idx];   // predicated coalesced load
        int lim = e1 - base;                     // valid items this chunk (>=1)
        if (lim > 32) lim = 32;
        int nr = (lim + 3) >> 2;                 // rounds of 4
        nr = (nr + 1) & ~1;                      // even # rounds (extras hit row N)
        for (int r = 0; r < nr; r += 2) {
            int sA = __shfl(sld, sb + ((r + 0) << 2) + es);
            int sB = __shfl(sld, sb + ((r + 1) << 2) + es);
            uint4 vA = rb[(size_t)sA * 8 + dg];
            uint4 vB = rb[(size_t)sB * 8 + dg];
            a0 += bflo(vA.x) + bflo(vB.x);
            a1 += bfhi(vA.x) + bfhi(vB.x);
            a2 += bflo(vA.y) + bflo(vB.y);
            a3 += bfhi(vA.y) + bfhi(vB.y);
            a4 += bflo(vA.z) + bflo(vB.z);
            a5 += bfhi(vA.z) + bfhi(vB.z);
            a6 += bflo(vA.w) + bflo(vB.w);
            a7 += bfhi(vA.w) + bfhi(vB.w);
        }
    }
    // reduce over edge slots (es bits 3..4 -> xor 8, 16; stays within half)
    #pragma unroll
    for (int m = 8; m <= 16; m <<= 1) {
        a0 += __shfl_xor(a0, m); a1 += __shfl_xor(a1, m);
        a2 += __shfl_xor(a2, m); a3 += __shfl_xor(a3, m);
        a4 += __shfl_xor(a4, m); a5 += __shfl_xor(a5, m);
        a6 += __shfl_xor(a6, m); a7 += __shfl_xor(a7, m);
    }
    if (es == 0) {
        float dn = dinv[n];
        float4 bA = ((const float4*)b1)[2 * dg];
        float4 bB = ((const float4*)b1)[2 * dg + 1];
        float r0 = fmaxf(fmaf(dn, a0, bA.x), 0.f);
        float r1 = fmaxf(fmaf(dn, a1, bA.y), 0.f);
        float r2 = fmaxf(fmaf(dn, a2, bA.z), 0.f);
        float r3 = fmaxf(fmaf(dn, a3, bA.w), 0.f);
        float r4 = fmaxf(fmaf(dn, a4, bB.x), 0.f);
        float r5 = fmaxf(fmaf(dn, a5, bB.y), 0.f);
        float r6 = fmaxf(fmaf(dn, a6, bB.z), 0.f);
        float r7 = fmaxf(fmaf(dn, a7, bB.w), 0.f);
        uint4 pv;
        pv.x = packbf2(r0, r1); pv.y = packbf2(r2, r3);
        pv.z = packbf2(r4, r5); pv.w = packbf2(r6, r7);
        ((uint4*)h1au)[(size_t)n * 8 + dg] = pv;
    }
}

// ---------------------------------------------------------------------------
// GEMM2: h2 = bf16( (h1a @ W2) * dinv[n] ), row = 8 uints. Row N = zeros.
// ---------------------------------------------------------------------------
__global__ __launch_bounds__(256) void gemm2_kernel(const unsigned* __restrict__ h1au,
                                                    const float* __restrict__ W2,
                                                    const float* __restrict__ dinv,
                                                    unsigned* __restrict__ h2u, int N) {
    __shared__ __align__(16) float sW[HID_DIM * OUT_DIM];  // 4 KB
    __shared__ __align__(16) float sx[16 * HID_DIM];       // 4 KB
    int t = threadIdx.x;
    int node0 = blockIdx.x * 16;

    ((float4*)sW)[t] = ((const float4*)W2)[t];
    for (int i = t; i < 512; i += 256) {           // 16 rows x 32 uints
        int r = i >> 5, c = i & 31;
        int n = node0 + r; if (n >= N) n = 0;      // clamp; dummy handled by dn=0
        unsigned v = h1au[(size_t)n * 32 + c];
        float2 f; f.x = bflo(v); f.y = bfhi(v);
        *(float2*)(sx + r * HID_DIM + 2 * c) = f;
    }
    __syncthreads();

    int ln = t >> 4, j = t & 15;
    float acc = 0.f;
    const float* xr = sx + ln * HID_DIM;
    #pragma unroll 8
    for (int k = 0; k < HID_DIM; ++k) acc += xr[k] * sW[k * OUT_DIM + j];
    int n = node0 + ln;
    float other = __shfl_xor(acc, 1);              // pair dims (j even, j odd)
    if (n <= N && (j & 1) == 0) {
        float dn = (n < N) ? dinv[n] : 0.f;        // row N -> zeros (agg2 zero-pad)
        h2u[(size_t)n * 8 + (j >> 1)] = packbf2(acc * dn, other * dn);
    }
}

// ---------------------------------------------------------------------------
// Aggregation layer 2 (v4): FOUR nodes per wave. lane = (h 2b, es 0..3,
// dg 0..3). uint2/lane (4 bf16 dims); one load = 16 edge rows (4/node).
// Indices: 16 consecutive per quarter. Reduce: 2 xor levels for all 4 nodes
// at once. h2u (1.6 MB) is L2-resident. out = dinv[n]*sum + b2, fp32.
// ---------------------------------------------------------------------------
__global__ __launch_bounds__(256) void agg2_kernel(const unsigned* __restrict__ h2u,
                                                   const int* __restrict__ row_ptr,
                                                   const int* __restrict__ csr_src,
                                                   const float* __restrict__ dinv,
                                                   const float* __restrict__ b2,
                                                   float* __restrict__ out, int N) {
    int t = threadIdx.x;
    int lane = t & 63;
    int h  = lane >> 4;            // node quarter 0..3
    int l  = lane & 15;
    int es = l >> 2;               // edge slot 0..3
    int dg = l & 3;                // dim group: uint2 = dims 4dg..4dg+3
    int n = blockIdx.x * 16 + ((t >> 6) << 2) + h; // 4 nodes/wave, 16/block
    if (n >= N) return;

    int e0 = row_ptr[n], e1 = row_ptr[n + 1];
    const uint2* rb = (const uint2*)h2u;     // row = 4 uint2
    int sb = h << 4;                          // shfl base for this quarter

    float a0 = 0.f, a1 = 0.f, a2 = 0.f, a3 = 0.f;

    for (int base = e0 - 1; base < e1; base += 16) {
        int idx = base + l;
        int sld = N;
        if (idx == e0 - 1) sld = n;
        else if (idx < e1) sld = csr_src[idx];
        int lim = e1 - base;
        if (lim > 16) lim = 16;
        int nr = (lim + 3) >> 2;                 // rounds of 4
        nr = (nr + 1) & ~1;                      // even (extras hit row N)
        for (int r = 0; r < nr; r += 2) {
            int sA = __shfl(sld, sb + ((r + 0) << 2) + es);
            int sB = __shfl(sld, sb + ((r + 1) << 2) + es);
            uint2 vA = rb[(size_t)sA * 4 + dg];
            uint2 vB = rb[(size_t)sB * 4 + dg];
            a0 += bflo(vA.x) + bflo(vB.x);
            a1 += bfhi(vA.x) + bfhi(vB.x);
            a2 += bflo(vA.y) + bflo(vB.y);
            a3 += bfhi(vA.y) + bfhi(vB.y);
        }
    }
    // reduce over edge slots (es bits 2..3 -> xor 4, 8; stays within quarter)
    #pragma unroll
    for (int m = 4; m <= 8; m <<= 1) {
        a0 += __shfl_xor(a0, m); a1 += __shfl_xor(a1, m);
        a2 += __shfl_xor(a2, m); a3 += __shfl_xor(a3, m);
    }
    if (es == 0) {
        float dn = dinv[n];
        float4 bb = ((const float4*)b2)[dg];
        float4 r;
        r.x = fmaf(dn, a0, bb.x);
        r.y = fmaf(dn, a1, bb.y);
        r.z = fmaf(dn, a2, bb.z);
        r.w = fmaf(dn, a3, bb.w);
        ((float4*)out)[(size_t)n * 4 + dg] = r;
    }
}

// ---------------------------------------------------------------------------
// Launch
// ---------------------------------------------------------------------------
extern "C" void kernel_launch(void* const* d_in, const int* in_sizes, int n_in,
                              void* d_out, int out_size, void* d_ws, size_t ws_size,
                              hipStream_t stream) {
    const float* x  = (const float*)d_in[0];
    const int*   ei = (const int*)d_in[1];
    const float* W1 = (const float*)d_in[2];
    const float* b1 = (const float*)d_in[3];
    const float* W2 = (const float*)d_in[4];
    const float* b2 = (const float*)d_in[5];
    float* out = (float*)d_out;

    const int N = in_sizes[0] / IN_DIM;   // 50000
    const int E = in_sizes[1] / 2;        // 1000000
    const int* src = ei;
    const int* dst = ei + E;

    const int NS  = (N + SMASK) >> SSHIFT;       // 391 stripes (<= 512)
    const int NSP = NS + 1;
    const int BC  = (E + CHUNK - 1) / CHUNK;     // 245 chunks (<= 256)

    char* w = (char*)d_ws;
    auto alloc = [&](size_t bytes) -> void* {
        void* p = (void*)w;
        w += (bytes + 255) & ~(size_t)255;
        return p;
    };
    int*      cm      = (int*)     alloc((size_t)256 * NSP * 4);
    int*      tot     = (int*)     alloc((size_t)NS * 4);
    int*      eb      = (int*)     alloc((size_t)E * 4);
    int*      csr_src = (int*)     alloc((size_t)E * 4);
    int*      row_ptr = (int*)     alloc((size_t)(N + 1) * 4);
    float*    dinv    = (float*)   alloc((size_t)N * 4);
    unsigned* h1u     = (unsigned*)alloc((size_t)(N + 1) * 32 * 4);  // bf16 [N+1][64]
    unsigned* h1au    = (unsigned*)alloc((size_t)(N + 1) * 32 * 4);
    unsigned* h2u     = (unsigned*)alloc((size_t)(N + 1) * 8 * 4);   // bf16 [N+1][16]

    const int GB  = (N + 16) / 16;   // covers rows 0..N (incl. dummy)
    const int AB1 = (N + 7) / 8;     // agg1: 8 nodes/block (2 per wave)
    const int AB2 = (N + 15) / 16;   // agg2: 16 nodes/block (4 per wave)

    passA <<<BC, CBLK, 0, stream>>>(dst, cm, E, NS, NSP);
    passB1<<<NS, 256,  0, stream>>>(cm, tot, BC, NSP);
    passC <<<BC, CBLK, 0, stream>>>(src, dst, cm, tot, eb, E, NS, NSP);
    passD <<<NS, 256,  0, stream>>>(eb, tot, csr_src, row_ptr, dinv, N, E, NS);

    gemm1_kernel<<<GB, 256, 0, stream>>>(x, W1, dinv, h1u, N);
    agg1_kernel<<<AB1, 256, 0, stream>>>(h1u, row_ptr, csr_src, dinv, b1, h1au, N);
    gemm2_kernel<<<GB, 256, 0, stream>>>(h1au, W2, dinv, h2u, N);
    agg2_kernel<<<AB2, 256, 0, stream>>>(h2u, row_ptr, csr_src, dinv, b2, out, N);
}